// Round 3
// baseline (184.065 us; speedup 1.0000x reference)
//
#include <hip/hip_runtime.h>
#include <hip/hip_fp16.h>
#include <math.h>

#define T_LEN 8192
#define CHN 128
#define BATCH 16
#define NKCHUNK 16   // k-chunk = 512 = 8 tiles of 64

typedef short bf16x8 __attribute__((ext_vector_type(8)));
typedef float f32x16 __attribute__((ext_vector_type(16)));

#define SIN8 0.3826834323650898f
#define COS8 0.9238795325112868f
#define SROW 72          // LDS row stride (ushorts) = 144 B, 16B-aligned
#define SPLANE (128 * SROW)

// Fence: nothing (twiddle sincos, address chains) may be scheduled across a
// pass boundary. R2 post-mortem: with all passes inlined, hoisting inflated
// whole-kernel pressure past the 64-VGPR @ 8 waves/EU budget -> 32 B/thread
// scratch spill (WRITE_SIZE 131 MB vs 65.5 MB output).
#define PASS_FENCE() __builtin_amdgcn_sched_barrier(0)

__device__ __forceinline__ ushort f2bf(float f) {
    unsigned u = __float_as_uint(f);
    unsigned r = (u + 0x7fffu + ((u >> 16) & 1u)) >> 16;
    return (ushort)r;
}

// Barrier that drains ONLY LDS ops (lgkmcnt), leaving global prefetch loads
// in flight (gram kernel).
__device__ __forceinline__ void barrier_lds_only() {
    asm volatile("s_waitcnt lgkmcnt(0)" ::: "memory");
    __builtin_amdgcn_s_barrier();
}

__device__ __forceinline__ float2 cadd(float2 a, float2 b) { return make_float2(a.x + b.x, a.y + b.y); }
__device__ __forceinline__ float2 csub(float2 a, float2 b) { return make_float2(a.x - b.x, a.y - b.y); }
__device__ __forceinline__ float2 cmul(float2 a, float2 b) {
    return make_float2(a.x * b.x - a.y * b.y, a.x * b.y + a.y * b.x);
}

__device__ __forceinline__ void r4f(float2 x0, float2 x1, float2 x2, float2 x3,
                                    float2 wa, float2 wb, float2 wc,
                                    float2& y0, float2& y1, float2& y2, float2& y3) {
    float2 t0 = cadd(x0, x2), t1 = csub(x0, x2);
    float2 t2 = cadd(x1, x3), t3 = csub(x1, x3);
    y0 = cadd(t0, t2);
    y1 = cmul(csub(t0, t2), wb);
    y2 = cmul(make_float2(t1.x + t3.y, t1.y - t3.x), wa);
    y3 = cmul(make_float2(t1.x - t3.y, t1.y + t3.x), wc);
}

__device__ __forceinline__ void r4i(float2 x0, float2 x1, float2 x2, float2 x3,
                                    float2 wa, float2 wb, float2 wc,
                                    float2& y0, float2& y1, float2& y2, float2& y3) {
    float2 a1 = cmul(x1, wb);
    float2 a2 = cmul(x2, wa);
    float2 a3 = cmul(x3, wc);
    float2 u0 = cadd(x0, a1), u1 = csub(x0, a1);
    float2 p = cadd(a2, a3);
    float2 m = make_float2(-(a2.y - a3.y), a2.x - a3.x);
    y0 = cadd(u0, p); y2 = csub(u0, p);
    y1 = cadd(u1, m); y3 = csub(u1, m);
}

// Forward radix-8 pass, store-as-computed: reads all 8, first r4f half,
// 4 stores, second r4f half, 4 stores. Peak live ~45 regs incl. addresses.
// Identical math to the old r8f (wr(0..3) = r4f(u), wr(4..7) = r4f(v)).
template <class RD, class WR>
__device__ __forceinline__ void pass_fwd(RD rd, WR wr, float sn, float cs) {
    const float r22 = 0.70710678118654752f;
    float2 xx[8];
#pragma unroll
    for (int c = 0; c < 8; ++c) xx[c] = rd(c);
    float2 w1 = make_float2(cs, sn);
    float2 w2 = make_float2(cs * cs - sn * sn, 2.f * cs * sn);
    float2 w4 = cmul(w2, w2);
    float2 w6 = cmul(w4, w2);
    float2 u0 = cadd(xx[0], xx[4]), u1 = cadd(xx[1], xx[5]);
    float2 u2 = cadd(xx[2], xx[6]), u3 = cadd(xx[3], xx[7]);
    float2 e0 = cmul(csub(xx[0], xx[4]), w1);
    float2 e1 = cmul(csub(xx[1], xx[5]), w1);
    float2 e2 = cmul(csub(xx[2], xx[6]), w1);
    float2 e3 = cmul(csub(xx[3], xx[7]), w1);
    float2 v0 = e0;
    float2 v1 = make_float2(r22 * (e1.x + e1.y), r22 * (e1.y - e1.x));
    float2 v2 = make_float2(e2.y, -e2.x);
    float2 v3 = make_float2(r22 * (e3.y - e3.x), -r22 * (e3.x + e3.y));
    float2 a, b, c2, d;
    r4f(u0, u1, u2, u3, w2, w4, w6, a, b, c2, d);
    wr(0, a); wr(1, b); wr(2, c2); wr(3, d);
    r4f(v0, v1, v2, v3, w2, w4, w6, a, b, c2, d);
    wr(4, a); wr(5, b); wr(6, c2); wr(7, d);
}

// Inverse radix-8 pass, split reads (4+4) and pairwise combine-and-store
// (y[k], y[k+4] stored as soon as t_k is formed). Identical math to old r8i.
template <class RD, class WR>
__device__ __forceinline__ void pass_inv(RD rd, WR wr, float sn, float cs) {
    const float r22 = 0.70710678118654752f;
    float2 w1 = make_float2(cs, sn);
    float2 w2 = make_float2(cs * cs - sn * sn, 2.f * cs * sn);
    float2 w4 = cmul(w2, w2);
    float2 w6 = cmul(w4, w2);
    float2 g0, g1, g2, g3, g4, g5, g6, g7;
    {
        float2 x0 = rd(0), x1 = rd(1), x2 = rd(2), x3 = rd(3);
        r4i(x0, x1, x2, x3, w2, w4, w6, g0, g1, g2, g3);
    }
    {
        float2 x4 = rd(4), x5 = rd(5), x6 = rd(6), x7 = rd(7);
        r4i(x4, x5, x6, x7, w2, w4, w6, g4, g5, g6, g7);
    }
    float2 t0 = cmul(g4, w1);
    wr(0, cadd(g0, t0)); wr(4, csub(g0, t0));
    float2 e1 = cmul(g5, w1);
    float2 t1 = make_float2(r22 * (e1.x - e1.y), r22 * (e1.x + e1.y));
    wr(1, cadd(g1, t1)); wr(5, csub(g1, t1));
    float2 e2 = cmul(g6, w1);
    float2 t2 = make_float2(-e2.y, e2.x);
    wr(2, cadd(g2, t2)); wr(6, csub(g2, t2));
    float2 e3 = cmul(g7, w1);
    float2 t3 = make_float2(-r22 * (e3.x + e3.y), r22 * (e3.x - e3.y));
    wr(3, cadd(g3, t3)); wr(7, csub(g3, t3));
}

// One block per (b,c) row, 1024 threads, 2 blocks/CU (32 waves/CU).
// R11: every pass is fenced with sched_barrier(0) at the __syncthreads()
// boundaries, and butterflies store-as-computed, so the per-pass live set
// (~45-50 VGPR) is the whole-kernel peak. Goal: genuinely fit the 64-VGPR
// budget of __launch_bounds__(1024, 8) -> no scratch spill.
__global__ __launch_bounds__(1024, 8) void fft_analytic_kernel(const float* __restrict__ x,
                                                               ushort* __restrict__ zc,
                                                               ushort* __restrict__ zs) {
    __shared__ __align__(16) float2 buf[T_LEN];   // 64 KiB
    const int u = threadIdx.x;
    const int row = blockIdx.x;
    const float* xr = x + ((size_t)row << 13);

    // pass A: fwd radix-8 stride 1024, fused with global load (x pure real:
    // 8 live floats, real-u branch stores c=0..3 directly)
    {
        const float r22 = 0.70710678118654752f;
        float X[8];
#pragma unroll
        for (int c = 0; c < 8; ++c) X[c] = xr[u + (c << 10)];
        float sn, cs;
        __sincosf(-(float)M_PI / 4096.f * (float)u, &sn, &cs);
        float2 w2 = make_float2(cs * cs - sn * sn, 2.f * cs * sn);
        float2 w4 = cmul(w2, w2);
        float2 w6 = cmul(w4, w2);
        float u0 = X[0] + X[4], u1 = X[1] + X[5], u2 = X[2] + X[6], u3 = X[3] + X[7];
        float d0 = X[0] - X[4], d1 = X[1] - X[5], d2 = X[2] - X[6], d3 = X[3] - X[7];
        float2 e1 = make_float2(d1 * cs, d1 * sn);
        float2 e2 = make_float2(d2 * cs, d2 * sn);
        float2 e3 = make_float2(d3 * cs, d3 * sn);
        float2 v0 = make_float2(d0 * cs, d0 * sn);
        float2 v1 = make_float2(r22 * (e1.x + e1.y), r22 * (e1.y - e1.x));
        float2 v2 = make_float2(e2.y, -e2.x);
        float2 v3 = make_float2(r22 * (e3.y - e3.x), -r22 * (e3.x + e3.y));
        float t0 = u0 + u2, t1 = u0 - u2, t2 = u1 + u3, t3 = u1 - u3;
        buf[u] = make_float2(t0 + t2, 0.f);
        float s1 = t0 - t2;
        buf[u + (1 << 10)] = make_float2(s1 * w4.x, s1 * w4.y);
        buf[u + (2 << 10)] = cmul(make_float2(t1, -t3), w2);
        buf[u + (3 << 10)] = cmul(make_float2(t1, t3), w6);
        float2 a, b, c2, d;
        r4f(v0, v1, v2, v3, w2, w4, w6, a, b, c2, d);
        buf[u + (4 << 10)] = a; buf[u + (5 << 10)] = b;
        buf[u + (6 << 10)] = c2; buf[u + (7 << 10)] = d;
    }
    PASS_FENCE(); __syncthreads(); PASS_FENCE();

    // pass B: fwd radix-8 stride 128
    {
        const int j = u & 127;
        const int i = ((u & ~127) << 3) | j;
        float sn, cs;
        __sincosf(-(float)M_PI / 512.f * (float)j, &sn, &cs);
        pass_fwd([&](int c) { return buf[i + (c << 7)]; },
                 [&](int c, float2 v) { buf[i + (c << 7)] = v; }, sn, cs);
    }
    PASS_FENCE(); __syncthreads(); PASS_FENCE();

    // pass C: fwd radix-8 stride 16; plain reads, parity-split swizzled writes.
    // Element p=16T+2C+O -> float2 slot 16T + 8O + 2*((C>>1)^(T&3)) + (C&1).
    {
        const int j = u & 15;
        const int i = ((u & ~15) << 3) | j;
        const int O = j & 1, q = j >> 2, h = (j >> 1) & 1;
        const int Tb = i >> 4;
        float sn, cs;
        __sincosf(-(float)M_PI / 64.f * (float)j, &sn, &cs);
        pass_fwd([&](int c) { return buf[i + (c << 4)]; },
                 [&](int c, float2 v) {
                     const int T = Tb + c;
                     buf[(T << 4) + (O << 3) + 2 * (q ^ (T & 3)) + h] = v;
                 }, sn, cs);
    }
    PASS_FENCE(); __syncthreads(); PASS_FENCE();

    // register middle over thread pairs: thread u=(2t+o) owns the o-parity
    // half (8 elems) of 16-group t. Last fwd stage (radix-8 @ stride 2) +
    // radix-2 mask fuse (t = E + O, shfl_xor) + first inverse stage.
    {
        const int t = u >> 1, o = u & 1;
        const int K = t & 3;
        const int Fb = (t << 3) + (o << 2);
        float4* bb = (float4*)buf;
        float2 z[8], y[8];
#pragma unroll
        for (int q = 0; q < 4; ++q) {
            float4 f = bb[Fb + (q ^ K)];
            z[2 * q]     = make_float2(f.x, f.y);
            z[2 * q + 1] = make_float2(f.z, f.w);
        }
        const float snf = o ? -SIN8 : 0.f;
        const float csf = o ? COS8 : 1.f;
        pass_fwd([&](int c) { return z[c]; },
                 [&](int c, float2 v) { y[c] = v; }, snf, csf);
#pragma unroll
        for (int c = 0; c < 8; ++c) {
            y[c].x += __shfl_xor(y[c].x, 1);
            y[c].y += __shfl_xor(y[c].y, 1);
        }
        const float sni = o ? SIN8 : 0.f;
        pass_inv([&](int c) { return y[c]; },
                 [&](int c, float2 v) {
                     buf[2 * (Fb + ((c >> 1) ^ K)) + (c & 1)] = v;
                 }, sni, csf);
    }
    PASS_FENCE(); __syncthreads(); PASS_FENCE();

    // pass D: inv radix-8 stride 16: parity-split swizzled reads, plain writes
    {
        const int j = u & 15;
        const int i = ((u & ~15) << 3) | j;
        const int O = j & 1, q = j >> 2, h = (j >> 1) & 1;
        const int Tb = i >> 4;
        float sn, cs;
        __sincosf((float)M_PI / 64.f * (float)j, &sn, &cs);
        pass_inv([&](int c) {
                     const int T = Tb + c;
                     return buf[(T << 4) + (O << 3) + 2 * (q ^ (T & 3)) + h];
                 },
                 [&](int c, float2 v) { buf[i + (c << 4)] = v; }, sn, cs);
    }
    PASS_FENCE(); __syncthreads(); PASS_FENCE();

    // pass E: inv radix-8 stride 128
    {
        const int j = u & 127;
        const int i = ((u & ~127) << 3) | j;
        float sn, cs;
        __sincosf((float)M_PI / 512.f * (float)j, &sn, &cs);
        pass_inv([&](int c) { return buf[i + (c << 7)]; },
                 [&](int c, float2 v) { buf[i + (c << 7)] = v; }, sn, cs);
    }
    PASS_FENCE(); __syncthreads(); PASS_FENCE();

    // pass F: inv radix-8 stride 1024 fused with normalize + store
    {
        ushort* zcr = zc + ((size_t)row << 13);
        ushort* zsr = zs + ((size_t)row << 13);
        float sn, cs;
        __sincosf((float)M_PI / 4096.f * (float)u, &sn, &cs);
        pass_inv([&](int c) { return buf[u + (c << 10)]; },
                 [&](int c, float2 vv) {
                     float n2 = vv.x * vv.x + vv.y * vv.y;
                     float cc = 1.f, ss = 0.f;
                     if (n2 > 0.f) { float inv = rsqrtf(n2); cc = vv.x * inv; ss = vv.y * inv; }
                     zcr[u + (c << 10)] = f2bf(cc);
                     zsr[u + (c << 10)] = f2bf(ss);
                 }, sn, cs);
    }
}

// MFMA Gram partials. grid=(BATCH, NKCHUNK), block=512 (8 waves, 2/SIMD).
// Depth-2 register prefetch + lgkm-only barriers: prefetch loads stay in
// flight across iterations (no per-iter vmcnt(0) drain). The ds_write's
// dependence on prefetched VGPRs gets the compiler's fine-grained vmcnt(N).
__global__ __launch_bounds__(512, 2) void gram_kernel(const ushort* __restrict__ zc,
                                                      const ushort* __restrict__ zs,
                                                      __half2* __restrict__ partial) {
    const int b = blockIdx.x, kc = blockIdx.y;
    const int tid = threadIdx.x;
    const int wave = tid >> 6;
    const int wr = wave & 3, wcol = wave >> 2;
    const int lane31 = tid & 31;
    const int half = (tid >> 5) & 1;

    __shared__ __align__(16) ushort sZ[2 * SPLANE];

    f32x16 accRe[2], accIm[2];
#pragma unroll
    for (int v = 0; v < 2; ++v)
#pragma unroll
        for (int r = 0; r < 16; ++r) { accRe[v][r] = 0.f; accIm[v][r] = 0.f; }

    const size_t base = ((size_t)b * CHN) << 13;
    const int k0 = kc << 9;   // *512

    const ushort* srcs[4];
    int ldst[4];
#pragma unroll
    for (int q = 0; q < 4; ++q) {
        int id = tid + (q << 9);                   // 0..2047 = plane*1024 + rid*8 + ck
        int plane = id >> 10;
        int rid = (id >> 3) & 127;
        int ck = id & 7;
        srcs[q] = (plane ? zs : zc) + base + ((size_t)rid << 13) + (size_t)(k0 + ck * 8);
        ldst[q] = plane * SPLANE + rid * SROW + ck * 8;
    }

    uint4 pre[2][4];
#pragma unroll
    for (int q = 0; q < 4; ++q) pre[0][q] = *(const uint4*)srcs[q];
#pragma unroll
    for (int q = 0; q < 4; ++q) pre[1][q] = *(const uint4*)(srcs[q] + 64);

#pragma unroll
    for (int it = 0; it < 8; ++it) {
        barrier_lds_only();                         // prev iter's ds_reads done
#pragma unroll
        for (int q = 0; q < 4; ++q) *(uint4*)&sZ[ldst[q]] = pre[it & 1][q];
        if (it < 6) {
#pragma unroll
            for (int q = 0; q < 4; ++q)
                pre[it & 1][q] = *(const uint4*)(srcs[q] + (it + 2) * 64);
        }
        barrier_lds_only();                         // ds_writes visible; vmem stays in flight
#pragma unroll
        for (int kb = 0; kb < 64; kb += 16) {
            const int aoff = (wr * 32 + lane31) * SROW + kb + half * 8;
            bf16x8 aC = *(const bf16x8*)&sZ[aoff];
            bf16x8 aS = *(const bf16x8*)&sZ[SPLANE + aoff];
            bf16x8 aCn;
#pragma unroll
            for (int r = 0; r < 8; ++r) aCn[r] = (short)(aC[r] ^ (short)0x8000);
            bf16x8 bC[2], bS[2];
#pragma unroll
            for (int v = 0; v < 2; ++v) {
                const int boff = (wcol * 64 + v * 32 + lane31) * SROW + kb + half * 8;
                bC[v] = *(const bf16x8*)&sZ[boff];
                bS[v] = *(const bf16x8*)&sZ[SPLANE + boff];
            }
            accRe[0] = __builtin_amdgcn_mfma_f32_32x32x16_bf16(aC,  bC[0], accRe[0], 0, 0, 0);
            accRe[1] = __builtin_amdgcn_mfma_f32_32x32x16_bf16(aC,  bC[1], accRe[1], 0, 0, 0);
            accIm[0] = __builtin_amdgcn_mfma_f32_32x32x16_bf16(aS,  bC[0], accIm[0], 0, 0, 0);
            accIm[1] = __builtin_amdgcn_mfma_f32_32x32x16_bf16(aS,  bC[1], accIm[1], 0, 0, 0);
            accRe[0] = __builtin_amdgcn_mfma_f32_32x32x16_bf16(aS,  bS[0], accRe[0], 0, 0, 0);
            accRe[1] = __builtin_amdgcn_mfma_f32_32x32x16_bf16(aS,  bS[1], accRe[1], 0, 0, 0);
            accIm[0] = __builtin_amdgcn_mfma_f32_32x32x16_bf16(aCn, bS[0], accIm[0], 0, 0, 0);
            accIm[1] = __builtin_amdgcn_mfma_f32_32x32x16_bf16(aCn, bS[1], accIm[1], 0, 0, 0);
        }
    }

    // C/D layout (verified m74/m101): col=lane&31, row=(reg&3)+8*(reg>>2)+4*(lane>>5)
    __half2* pb = partial + ((size_t)(kc * BATCH + b) << 14);
#pragma unroll
    for (int v = 0; v < 2; ++v)
#pragma unroll
        for (int r = 0; r < 16; ++r) {
            int rrow = (r & 3) + 8 * (r >> 2) + 4 * half;
            int i = wr * 32 + rrow;
            int j = wcol * 64 + v * 32 + lane31;
            pb[i * CHN + j] = __floats2half2_rn(accRe[v][r], accIm[v][r]);
        }
}

__global__ __launch_bounds__(256) void reduce_kernel(const __half2* __restrict__ partial,
                                                     float* __restrict__ out) {
    const size_t i = (size_t)blockIdx.x * 256 + threadIdx.x;
    const size_t n = (size_t)BATCH * CHN * CHN;
    if (i >= n) return;
    float re = 0.0f, im = 0.0f;
#pragma unroll
    for (int c = 0; c < NKCHUNK; ++c) {
        float2 p = __half22float2(partial[(size_t)c * n + i]);
        re += p.x;
        im += p.y;
    }
    out[i] = sqrtf(re * re + im * im) * (1.0f / (float)T_LEN);
}

extern "C" void kernel_launch(void* const* d_in, const int* in_sizes, int n_in,
                              void* d_out, int out_size, void* d_ws, size_t ws_size,
                              hipStream_t stream) {
    const float* x = (const float*)d_in[0];
    float* out = (float*)d_out;

    const size_t plane_elems = (size_t)BATCH * CHN * T_LEN;                 // 16.8M
    ushort* zc = (ushort*)d_ws;                                             // 33.55 MB
    ushort* zs = zc + plane_elems;                                          // +33.55 MB
    __half2* partial = (__half2*)((char*)d_ws + 2 * plane_elems * sizeof(ushort)); // +16.78 MB

    fft_analytic_kernel<<<BATCH * CHN, 1024, 0, stream>>>(x, zc, zs);

    dim3 g2(BATCH, NKCHUNK);
    gram_kernel<<<g2, 512, 0, stream>>>(zc, zs, partial);

    const int n_out = BATCH * CHN * CHN;
    reduce_kernel<<<(n_out + 255) / 256, 256, 0, stream>>>(partial, out);
}

// Round 4
// 179.384 us; speedup vs baseline: 1.0261x; 1.0261x over previous
//
#include <hip/hip_runtime.h>
#include <hip/hip_fp16.h>
#include <math.h>

#define T_LEN 8192
#define CHN 128
#define BATCH 16
#define NKCHUNK 32   // R12: k-chunk = 256 = 4 tiles of 64 (was 16/512/8) -> 512 blocks = 2/CU
#define NITER (T_LEN / NKCHUNK / 64)   // stage iterations per block = 4

typedef short bf16x8 __attribute__((ext_vector_type(8)));
typedef float f32x16 __attribute__((ext_vector_type(16)));

#define SIN8 0.3826834323650898f
#define COS8 0.9238795325112868f
#define SROW 72          // LDS row stride (ushorts) = 144 B, 16B-aligned
#define SPLANE (128 * SROW)

__device__ __forceinline__ ushort f2bf(float f) {
    unsigned u = __float_as_uint(f);
    unsigned r = (u + 0x7fffu + ((u >> 16) & 1u)) >> 16;
    return (ushort)r;
}

// Barrier that drains ONLY LDS ops (lgkmcnt), leaving global prefetch loads
// in flight. __syncthreads() emits s_waitcnt vmcnt(0) before s_barrier, which
// drains the depth-2 prefetch every iteration — the gram 66-us stall (R8 pm).
__device__ __forceinline__ void barrier_lds_only() {
    asm volatile("s_waitcnt lgkmcnt(0)" ::: "memory");
    __builtin_amdgcn_s_barrier();
}

__device__ __forceinline__ float2 cadd(float2 a, float2 b) { return make_float2(a.x + b.x, a.y + b.y); }
__device__ __forceinline__ float2 csub(float2 a, float2 b) { return make_float2(a.x - b.x, a.y - b.y); }
__device__ __forceinline__ float2 cmul(float2 a, float2 b) {
    return make_float2(a.x * b.x - a.y * b.y, a.x * b.y + a.y * b.x);
}

__device__ __forceinline__ void r4f(float2 x0, float2 x1, float2 x2, float2 x3,
                                    float2 wa, float2 wb, float2 wc,
                                    float2& y0, float2& y1, float2& y2, float2& y3) {
    float2 t0 = cadd(x0, x2), t1 = csub(x0, x2);
    float2 t2 = cadd(x1, x3), t3 = csub(x1, x3);
    y0 = cadd(t0, t2);
    y1 = cmul(csub(t0, t2), wb);
    y2 = cmul(make_float2(t1.x + t3.y, t1.y - t3.x), wa);
    y3 = cmul(make_float2(t1.x - t3.y, t1.y + t3.x), wc);
}

__device__ __forceinline__ void r4i(float2 x0, float2 x1, float2 x2, float2 x3,
                                    float2 wa, float2 wb, float2 wc,
                                    float2& y0, float2& y1, float2& y2, float2& y3) {
    float2 a1 = cmul(x1, wb);
    float2 a2 = cmul(x2, wa);
    float2 a3 = cmul(x3, wc);
    float2 u0 = cadd(x0, a1), u1 = csub(x0, a1);
    float2 p = cadd(a2, a3);
    float2 m = make_float2(-(a2.y - a3.y), a2.x - a3.x);
    y0 = cadd(u0, p); y2 = csub(u0, p);
    y1 = cadd(u1, m); y3 = csub(u1, m);
}

__device__ __forceinline__ void r8f(const float2* x, float sn, float cs, float2* y) {
    const float r22 = 0.70710678118654752f;
    float2 w1 = make_float2(cs, sn);
    float2 w2 = make_float2(cs * cs - sn * sn, 2.f * cs * sn);
    float2 w4 = cmul(w2, w2);
    float2 w6 = cmul(w4, w2);
    float2 u0 = cadd(x[0], x[4]), u1 = cadd(x[1], x[5]), u2 = cadd(x[2], x[6]), u3 = cadd(x[3], x[7]);
    float2 e0 = cmul(csub(x[0], x[4]), w1);
    float2 e1 = cmul(csub(x[1], x[5]), w1);
    float2 e2 = cmul(csub(x[2], x[6]), w1);
    float2 e3 = cmul(csub(x[3], x[7]), w1);
    float2 v0 = e0;
    float2 v1 = make_float2(r22 * (e1.x + e1.y), r22 * (e1.y - e1.x));
    float2 v2 = make_float2(e2.y, -e2.x);
    float2 v3 = make_float2(r22 * (e3.y - e3.x), -r22 * (e3.x + e3.y));
    r4f(u0, u1, u2, u3, w2, w4, w6, y[0], y[1], y[2], y[3]);
    r4f(v0, v1, v2, v3, w2, w4, w6, y[4], y[5], y[6], y[7]);
}

__device__ __forceinline__ void r8i(const float2* x, float sn, float cs, float2* y) {
    const float r22 = 0.70710678118654752f;
    float2 w1 = make_float2(cs, sn);
    float2 w2 = make_float2(cs * cs - sn * sn, 2.f * cs * sn);
    float2 w4 = cmul(w2, w2);
    float2 w6 = cmul(w4, w2);
    float2 g0, g1, g2, g3, g4, g5, g6, g7;
    r4i(x[0], x[1], x[2], x[3], w2, w4, w6, g0, g1, g2, g3);
    r4i(x[4], x[5], x[6], x[7], w2, w4, w6, g4, g5, g6, g7);
    float2 t0 = cmul(g4, w1);
    float2 e1 = cmul(g5, w1);
    float2 e2 = cmul(g6, w1);
    float2 e3 = cmul(g7, w1);
    float2 t1 = make_float2(r22 * (e1.x - e1.y), r22 * (e1.x + e1.y));
    float2 t2 = make_float2(-e2.y, e2.x);
    float2 t3 = make_float2(-r22 * (e3.x + e3.y), r22 * (e3.x - e3.y));
    y[0] = cadd(g0, t0); y[4] = csub(g0, t0);
    y[1] = cadd(g1, t1); y[5] = csub(g1, t1);
    y[2] = cadd(g2, t2); y[6] = csub(g2, t2);
    y[3] = cadd(g3, t3); y[7] = csub(g3, t3);
}

// One block per (b,c) row, 512 threads — EXACT R0 revert (verified: 101 us,
// VGPR 60, zero spill). R1-R3 post-mortems: every __launch_bounds__(1024,8)
// variant spilled ~24-32 B/thread (VGPR_Count pinned at 32, WRITE_SIZE
// 114-131 MB vs 65.5 MB output) regardless of source restructure, and the
// spill stream evicted zc/zs from L2/L3, slowing gram by ~25-40 us. The
// 1024-thread occupancy theory is falsified; do not revisit.
__global__ __launch_bounds__(512, 4) void fft_analytic_kernel(const float* __restrict__ x,
                                                              ushort* __restrict__ zc,
                                                              ushort* __restrict__ zs) {
    __shared__ __align__(16) float2 buf[T_LEN];   // 64 KiB
    const int tid = threadIdx.x;
    const int row = blockIdx.x;
    const float* xr = x + ((size_t)row << 13);

    // fwd pass Q=1024 fused with global load (x real; imag folds away)
    for (int s = 0; s < 2; ++s) {
        const int g = tid + (s << 9);
        float2 X[8], Y[8];
#pragma unroll
        for (int c = 0; c < 8; ++c) X[c] = make_float2(xr[g + (c << 10)], 0.f);
        float sn, cs;
        __sincosf(-(float)M_PI / 4096.f * (float)g, &sn, &cs);
        r8f(X, sn, cs, Y);
#pragma unroll
        for (int c = 0; c < 8; ++c) buf[g + (c << 10)] = Y[c];
    }
    __syncthreads();

    // fwd LDS pass Q=128
    {
        const float astep = -(float)M_PI / 512.f;
        for (int s = 0; s < 2; ++s) {
            const int g = tid + (s << 9);
            const int j = g & 127;
            const int i = ((g & ~127) << 3) | j;
            float2 xx[8], yy[8];
#pragma unroll
            for (int c = 0; c < 8; ++c) xx[c] = buf[i + c * 128];
            float sn, cs;
            __sincosf(astep * (float)j, &sn, &cs);
            r8f(xx, sn, cs, yy);
#pragma unroll
            for (int c = 0; c < 8; ++c) buf[i + c * 128] = yy[c];
        }
        __syncthreads();
    }

    // fwd LDS pass Q=16: plain reads, swizzled writes (slot = idx ^ 2c)
    {
        const float astep = -(float)M_PI / 64.f;
        for (int s = 0; s < 2; ++s) {
            const int g = tid + (s << 9);
            const int j = g & 15;
            const int i = ((g & ~15) << 3) | j;
            float2 xx[8], yy[8];
#pragma unroll
            for (int c = 0; c < 8; ++c) xx[c] = buf[i + c * 16];
            float sn, cs;
            __sincosf(astep * (float)j, &sn, &cs);
            r8f(xx, sn, cs, yy);
#pragma unroll
            for (int c = 0; c < 8; ++c) buf[(i + c * 16) ^ (2 * c)] = yy[c];
        }
        __syncthreads();
    }

    // register-local middle: thread owns elements [16*tid, 16*tid+16).
    // Element-float4 (8*tid+p) lives at slot4 (8*tid + (p^(tid&7))).
    {
        float2 v[16];
        float4* bb = (float4*)buf;
        const int K = tid & 7;
#pragma unroll
        for (int p = 0; p < 8; ++p) {
            float4 f = bb[8 * tid + (p ^ K)];
            v[2 * p]     = make_float2(f.x, f.y);
            v[2 * p + 1] = make_float2(f.z, f.w);
        }
        float2 xe[8], xo[8], E[8], O[8], t[8];
#pragma unroll
        for (int c = 0; c < 8; ++c) { xe[c] = v[2 * c]; xo[c] = v[2 * c + 1]; }
        r8f(xe, 0.f, 1.f, E);
        r8f(xo, -SIN8, COS8, O);
#pragma unroll
        for (int c = 0; c < 8; ++c) t[c] = cadd(E[c], O[c]);   // dist-1 + mask fuse
        r8i(t, 0.f, 1.f, xe);
        r8i(t, SIN8, COS8, xo);
#pragma unroll
        for (int p = 0; p < 8; ++p)
            bb[8 * tid + (p ^ K)] = make_float4(xe[p].x, xe[p].y, xo[p].x, xo[p].y);
    }
    __syncthreads();

    // inv LDS pass Q=16: swizzled reads, plain writes
    {
        const float astep = (float)M_PI / 64.f;
        for (int s = 0; s < 2; ++s) {
            const int g = tid + (s << 9);
            const int j = g & 15;
            const int i = ((g & ~15) << 3) | j;
            float2 xx[8], yy[8];
#pragma unroll
            for (int c = 0; c < 8; ++c) xx[c] = buf[(i + c * 16) ^ (2 * c)];
            float sn, cs;
            __sincosf(astep * (float)j, &sn, &cs);
            r8i(xx, sn, cs, yy);
#pragma unroll
            for (int c = 0; c < 8; ++c) buf[i + c * 16] = yy[c];
        }
        __syncthreads();
    }

    // inv LDS pass Q=128
    {
        const float astep = (float)M_PI / 512.f;
        for (int s = 0; s < 2; ++s) {
            const int g = tid + (s << 9);
            const int j = g & 127;
            const int i = ((g & ~127) << 3) | j;
            float2 xx[8], yy[8];
#pragma unroll
            for (int c = 0; c < 8; ++c) xx[c] = buf[i + c * 128];
            float sn, cs;
            __sincosf(astep * (float)j, &sn, &cs);
            r8i(xx, sn, cs, yy);
#pragma unroll
            for (int c = 0; c < 8; ++c) buf[i + c * 128] = yy[c];
        }
        __syncthreads();
    }

    // final inv pass Q=1024 fused with normalize + contiguous row-major store
    ushort* zcr = zc + ((size_t)row << 13);
    ushort* zsr = zs + ((size_t)row << 13);
    for (int s = 0; s < 2; ++s) {
        const int g = tid + (s << 9);
        float2 xx[8], yy[8];
#pragma unroll
        for (int c = 0; c < 8; ++c) xx[c] = buf[g + (c << 10)];
        float sn, cs;
        __sincosf((float)M_PI / 4096.f * (float)g, &sn, &cs);
        r8i(xx, sn, cs, yy);
#pragma unroll
        for (int c = 0; c < 8; ++c) {
            float2 vv = yy[c];
            float n2 = vv.x * vv.x + vv.y * vv.y;
            float cc = 1.f, ss = 0.f;
            if (n2 > 0.f) { float inv = rsqrtf(n2); cc = vv.x * inv; ss = vv.y * inv; }
            zcr[g + (c << 10)] = f2bf(cc);
            zsr[g + (c << 10)] = f2bf(ss);
        }
    }
}

// MFMA Gram partials. R12: grid=(BATCH, NKCHUNK=32) = 512 blocks -> 2
// blocks/CU (was 256 = exactly 1/CU). Gram's floor is ~2 us MFMA / ~8 us
// LDS / ~11 us HBM but it ran ~70 us: with one block per CU all 8 waves
// sit in the same lgkm-barrier lockstep — no overlap of stage phase with
// MFMA phase. A second resident block provides cross-block overlap (T3-
// style role diversity); s_setprio(1) around the MFMA cluster biases the
// CU scheduler toward the compute-phase block (T5 — pays only with phase
// diversity, which 2 blocks/CU now provides).
__global__ __launch_bounds__(512, 2) void gram_kernel(const ushort* __restrict__ zc,
                                                      const ushort* __restrict__ zs,
                                                      __half2* __restrict__ partial) {
    const int b = blockIdx.x, kc = blockIdx.y;
    const int tid = threadIdx.x;
    const int wave = tid >> 6;
    const int wr = wave & 3, wcol = wave >> 2;
    const int lane31 = tid & 31;
    const int half = (tid >> 5) & 1;

    __shared__ __align__(16) ushort sZ[2 * SPLANE];

    f32x16 accRe[2], accIm[2];
#pragma unroll
    for (int v = 0; v < 2; ++v)
#pragma unroll
        for (int r = 0; r < 16; ++r) { accRe[v][r] = 0.f; accIm[v][r] = 0.f; }

    const size_t base = ((size_t)b * CHN) << 13;
    const int k0 = kc << 8;   // *256 (k-chunk)

    const ushort* srcs[4];
    int ldst[4];
#pragma unroll
    for (int q = 0; q < 4; ++q) {
        int id = tid + (q << 9);                   // 0..2047 = plane*1024 + rid*8 + ck
        int plane = id >> 10;
        int rid = (id >> 3) & 127;
        int ck = id & 7;
        srcs[q] = (plane ? zs : zc) + base + ((size_t)rid << 13) + (size_t)(k0 + ck * 8);
        ldst[q] = plane * SPLANE + rid * SROW + ck * 8;
    }

    uint4 pre[2][4];
#pragma unroll
    for (int q = 0; q < 4; ++q) pre[0][q] = *(const uint4*)srcs[q];
#pragma unroll
    for (int q = 0; q < 4; ++q) pre[1][q] = *(const uint4*)(srcs[q] + 64);

#pragma unroll
    for (int it = 0; it < NITER; ++it) {
        barrier_lds_only();                         // prev iter's ds_reads done
#pragma unroll
        for (int q = 0; q < 4; ++q) *(uint4*)&sZ[ldst[q]] = pre[it & 1][q];
        if (it < NITER - 2) {
#pragma unroll
            for (int q = 0; q < 4; ++q)
                pre[it & 1][q] = *(const uint4*)(srcs[q] + (it + 2) * 64);
        }
        barrier_lds_only();                         // ds_writes visible; vmem stays in flight
#pragma unroll
        for (int kb = 0; kb < 64; kb += 16) {
            const int aoff = (wr * 32 + lane31) * SROW + kb + half * 8;
            bf16x8 aC = *(const bf16x8*)&sZ[aoff];
            bf16x8 aS = *(const bf16x8*)&sZ[SPLANE + aoff];
            bf16x8 aCn;
#pragma unroll
            for (int r = 0; r < 8; ++r) aCn[r] = (short)(aC[r] ^ (short)0x8000);
            bf16x8 bC[2], bS[2];
#pragma unroll
            for (int v = 0; v < 2; ++v) {
                const int boff = (wcol * 64 + v * 32 + lane31) * SROW + kb + half * 8;
                bC[v] = *(const bf16x8*)&sZ[boff];
                bS[v] = *(const bf16x8*)&sZ[SPLANE + boff];
            }
            __builtin_amdgcn_s_setprio(1);
            accRe[0] = __builtin_amdgcn_mfma_f32_32x32x16_bf16(aC,  bC[0], accRe[0], 0, 0, 0);
            accRe[1] = __builtin_amdgcn_mfma_f32_32x32x16_bf16(aC,  bC[1], accRe[1], 0, 0, 0);
            accIm[0] = __builtin_amdgcn_mfma_f32_32x32x16_bf16(aS,  bC[0], accIm[0], 0, 0, 0);
            accIm[1] = __builtin_amdgcn_mfma_f32_32x32x16_bf16(aS,  bC[1], accIm[1], 0, 0, 0);
            accRe[0] = __builtin_amdgcn_mfma_f32_32x32x16_bf16(aS,  bS[0], accRe[0], 0, 0, 0);
            accRe[1] = __builtin_amdgcn_mfma_f32_32x32x16_bf16(aS,  bS[1], accRe[1], 0, 0, 0);
            accIm[0] = __builtin_amdgcn_mfma_f32_32x32x16_bf16(aCn, bS[0], accIm[0], 0, 0, 0);
            accIm[1] = __builtin_amdgcn_mfma_f32_32x32x16_bf16(aCn, bS[1], accIm[1], 0, 0, 0);
            __builtin_amdgcn_s_setprio(0);
        }
    }

    // C/D layout (verified m74/m101): col=lane&31, row=(reg&3)+8*(reg>>2)+4*(lane>>5)
    __half2* pb = partial + ((size_t)(kc * BATCH + b) << 14);
#pragma unroll
    for (int v = 0; v < 2; ++v)
#pragma unroll
        for (int r = 0; r < 16; ++r) {
            int rrow = (r & 3) + 8 * (r >> 2) + 4 * half;
            int i = wr * 32 + rrow;
            int j = wcol * 64 + v * 32 + lane31;
            pb[i * CHN + j] = __floats2half2_rn(accRe[v][r], accIm[v][r]);
        }
}

__global__ __launch_bounds__(256) void reduce_kernel(const __half2* __restrict__ partial,
                                                     float* __restrict__ out) {
    const size_t i = (size_t)blockIdx.x * 256 + threadIdx.x;
    const size_t n = (size_t)BATCH * CHN * CHN;
    if (i >= n) return;
    float re = 0.0f, im = 0.0f;
#pragma unroll
    for (int c = 0; c < NKCHUNK; ++c) {
        float2 p = __half22float2(partial[(size_t)c * n + i]);
        re += p.x;
        im += p.y;
    }
    out[i] = sqrtf(re * re + im * im) * (1.0f / (float)T_LEN);
}

extern "C" void kernel_launch(void* const* d_in, const int* in_sizes, int n_in,
                              void* d_out, int out_size, void* d_ws, size_t ws_size,
                              hipStream_t stream) {
    const float* x = (const float*)d_in[0];
    float* out = (float*)d_out;

    const size_t plane_elems = (size_t)BATCH * CHN * T_LEN;                 // 16.8M
    ushort* zc = (ushort*)d_ws;                                             // 33.55 MB
    ushort* zs = zc + plane_elems;                                          // +33.55 MB
    __half2* partial = (__half2*)((char*)d_ws + 2 * plane_elems * sizeof(ushort)); // +33.55 MB (NKCHUNK=32)

    fft_analytic_kernel<<<BATCH * CHN, 512, 0, stream>>>(x, zc, zs);

    dim3 g2(BATCH, NKCHUNK);
    gram_kernel<<<g2, 512, 0, stream>>>(zc, zs, partial);

    const int n_out = BATCH * CHN * CHN;
    reduce_kernel<<<(n_out + 255) / 256, 256, 0, stream>>>(partial, out);
}